// Round 7
// baseline (493.425 us; speedup 1.0000x reference)
//
#include <hip/hip_runtime.h>
#include <hip/hip_bf16.h>

#define E_TOT   100000
#define N_NODES 10000
#define DIMV    80
#define HID     64
#define EDIM    32
#define WNUM    2304
#define TE      32

static constexpr float NORMF      = 0.14433756729740643f;  // 1/sqrt(48)
static constexpr float INV_SQRT3F = 0.57735026918962576f;
static constexpr float RS32       = 0.17677669529663687f;  // 1/sqrt(32)
static constexpr float RS16       = 0.25f;                 // 1/sqrt(16)

typedef __attribute__((ext_vector_type(8))) short bf16x8;
typedef __attribute__((ext_vector_type(4))) float f32x4;

static __device__ __forceinline__ ushort f2bf(float v) {
    __hip_bfloat16 h(v);
    return *reinterpret_cast<ushort*>(&h);
}

// Coalesced transpose + bf16 convert: W2 (HID x WNUM fp32) -> W2T (WNUM x HID bf16)
__global__ __launch_bounds__(256) void prep_w2t(const float* __restrict__ W2,
                                                ushort* __restrict__ W2T) {
    __shared__ float sT[64][65];
    const int j0 = blockIdx.x * 64;
    #pragma unroll
    for (int k = 0; k < 16; ++k) {
        int idx = threadIdx.x + k*256;
        int t = idx >> 6, j = idx & 63;
        sT[j][t] = W2[t*WNUM + j0 + j];
    }
    __syncthreads();
    #pragma unroll
    for (int k = 0; k < 16; ++k) {
        int idx = threadIdx.x + k*256;
        int j = idx >> 6, t = idx & 63;
        W2T[(size_t)(j0 + j)*64 + t] = f2bf(sT[j][t]);
    }
}

// ---- CSR build (sort edges by dst) ----
__global__ __launch_bounds__(256) void hist_kernel(const int* __restrict__ dst,
                                                   int* __restrict__ hist) {
    int e = blockIdx.x*256 + threadIdx.x;
    if (e < E_TOT) atomicAdd(&hist[dst[e]], 1);
}

__global__ __launch_bounds__(256) void scan_kernel(const int* __restrict__ hist,
                                                   int* __restrict__ offs,
                                                   float* __restrict__ cntf) {
    __shared__ int part[256];
    const int t = threadIdx.x;
    const int base = t * 40;              // 256*40 = 10240 >= N_NODES
    int s = 0;
    for (int i = 0; i < 40; ++i) { int n = base + i; if (n < N_NODES) s += hist[n]; }
    part[t] = s; __syncthreads();
    for (int d = 1; d < 256; d <<= 1) {
        int v = 0; if (t >= d) v = part[t - d];
        __syncthreads();
        if (t >= d) part[t] += v;
        __syncthreads();
    }
    int run = (t > 0) ? part[t-1] : 0;
    for (int i = 0; i < 40; ++i) {
        int n = base + i;
        if (n < N_NODES) {
            offs[n] = run;
            int h = hist[n];
            run += h;
            cntf[n] = (float)(h > 0 ? h : 1);
        }
    }
}

__global__ __launch_bounds__(256) void scatter_kernel(const int* __restrict__ dst,
                                                      int* __restrict__ cursor,
                                                      const int* __restrict__ offs,
                                                      int* __restrict__ eidx) {
    int e = blockIdx.x*256 + threadIdx.x;
    if (e < E_TOT) {
        int d = dst[e];
        int p = atomicAdd(&cursor[d], 1);
        eidx[offs[d] + p] = e;
    }
}

// Edge kernel. MODE 0: contiguous edges + per-lane atomic scatter (fallback,
// round-5 behavior). MODE 1: sorted edges (gather by eidx) + LDS segment-
// reduce over equal-dst runs -> one atomicAdd per distinct (dst,k).
template<int MODE>
__global__ __launch_bounds__(256, 4) void edge_kernel(
    const int* __restrict__ dst, const int* __restrict__ eidx,
    const float* __restrict__ x_src, const float* __restrict__ sh,
    const float* __restrict__ ea, const float* __restrict__ W1,
    const float* __restrict__ b1, const ushort* __restrict__ W2T,
    const float* __restrict__ b2, float* __restrict__ sums,
    float* __restrict__ cnt)
{
    __shared__ float  sX[TE][81];
    __shared__ float  sSh[TE][4];
    __shared__ float  sXs1[TE][17];
    __shared__ float  sEcA[TE][33];
    __shared__ ushort sHbf[TE][HID];
    __shared__ float  sMsg[TE][84];
    __shared__ int    sDst[TE];
    __shared__ int    sEid[TE];

    const int tid  = threadIdx.x;
    const int lane = tid & 63;
    const int wave = tid >> 6;
    const int e0   = blockIdx.x * TE;

    if (MODE == 0) {
        if (tid < TE) { sEid[tid] = e0 + tid; sDst[tid] = dst[e0 + tid]; }
    } else {
        if (tid < TE) { int eid = eidx[e0 + tid]; sEid[tid] = eid; sDst[tid] = dst[eid]; }
    }
    __syncthreads();

    for (int i = tid; i < TE*DIMV; i += 256) { int e = i/80, k = i-e*80; sX[e][k] = x_src[(size_t)sEid[e]*DIMV + k]; }
    for (int i = tid; i < TE*EDIM; i += 256) { int e = i>>5, k = i&31; sEcA[e][k] = ea[(size_t)sEid[e]*EDIM + k]; }
    for (int i = tid; i < TE*4;    i += 256) { int e = i>>2, k = i&3;  sSh[e][k]  = sh[(size_t)sEid[e]*4 + k]; }
    __syncthreads();

    #pragma unroll
    for (int k = 0; k < (TE*HID)/256; ++k) {
        int idx = tid + k*256;
        int e = idx >> 6, t = idx & 63;
        float h = b1[t];
        #pragma unroll
        for (int i = 0; i < EDIM; ++i) h = fmaf(sEcA[e][i], W1[i*HID + t], h);
        sHbf[e][t] = f2bf(fmaxf(h, 0.f));
    }
    __syncthreads();

    for (int i = tid; i < TE*32; i += 256) {
        int e = i >> 5, u = i & 31;
        sEcA[e][u] = sSh[e][0] * sX[e][u];
    }
    for (int i = tid; i < TE*16; i += 256) {
        int e = i >> 4, u = i & 15;
        sXs1[e][u] = INV_SQRT3F * (sX[e][32+u*3+0]*sSh[e][1] +
                                   sX[e][32+u*3+1]*sSh[e][2] +
                                   sX[e][32+u*3+2]*sSh[e][3]);
    }
    for (int i = tid; i < TE*84; i += 256) sMsg[0][i] = 0.f;
    __syncthreads();

    const int c     = lane & 15;
    const int g     = lane >> 4;
    const int rbase = g << 2;
    bf16x8 afrag[2][2];
    #pragma unroll
    for (int rt = 0; rt < 2; ++rt)
        #pragma unroll
        for (int kt = 0; kt < 2; ++kt)
            afrag[rt][kt] = *reinterpret_cast<const bf16x8*>(&sHbf[rt*16 + c][kt*32 + g*8]);

    float pA[8]     = {};
    float sC2[8]    = {};
    float sDv[8][3] = {};

    auto tile_mfma = [&](int t16, f32x4& a0, f32x4& a1) {
        const int j0 = t16 << 4;
        const ushort* bp = W2T + (((size_t)(j0 + c)) << 6) + (g << 3);
        bf16x8 bf0 = *reinterpret_cast<const bf16x8*>(bp);
        bf16x8 bf1 = *reinterpret_cast<const bf16x8*>(bp + 32);
        const float bv = b2[j0 + c];
        a0 = {bv, bv, bv, bv};
        a1 = {bv, bv, bv, bv};
        a0 = __builtin_amdgcn_mfma_f32_16x16x32_bf16(afrag[0][0], bf0, a0, 0, 0, 0);
        a0 = __builtin_amdgcn_mfma_f32_16x16x32_bf16(afrag[0][1], bf1, a0, 0, 0, 0);
        a1 = __builtin_amdgcn_mfma_f32_16x16x32_bf16(afrag[1][0], bf0, a1, 0, 0, 0);
        a1 = __builtin_amdgcn_mfma_f32_16x16x32_bf16(afrag[1][1], bf1, a1, 0, 0, 0);
    };

    #pragma unroll 2
    for (int k = 0; k < 16; ++k) {
        const int t16 = wave + (k << 2);
        f32x4 a0, a1; tile_mfma(t16, a0, a1);
        const int u = t16 >> 1;
        #pragma unroll
        for (int r = 0; r < 4; ++r) {
            pA[r]   = fmaf(sEcA[rbase + r][u],      a0[r], pA[r]);
            pA[4+r] = fmaf(sEcA[16 + rbase + r][u], a1[r], pA[4+r]);
        }
    }
    #pragma unroll 2
    for (int k = 0; k < 8; ++k) {
        const int t16 = 64 + wave + (k << 2);
        f32x4 a0, a1; tile_mfma(t16, a0, a1);
        const int u = t16 - 64;
        #pragma unroll
        for (int r = 0; r < 4; ++r) {
            sC2[r]   = fmaf(sX[rbase + r][u],      a0[r], sC2[r]);
            sC2[4+r] = fmaf(sX[16 + rbase + r][u], a1[r], sC2[4+r]);
        }
    }
    #pragma unroll
    for (int k = 0; k < 4; ++k) {
        const int t16 = 96 + wave + (k << 2);
        f32x4 a0, a1; tile_mfma(t16, a0, a1);
        const int u = t16 - 96;
        #pragma unroll
        for (int r = 0; r < 4; ++r) {
            #pragma unroll
            for (int m = 0; m < 3; ++m) {
                sDv[r][m]   = fmaf(sX[rbase + r][32 + u*3 + m],      a0[r], sDv[r][m]);
                sDv[4+r][m] = fmaf(sX[16 + rbase + r][32 + u*3 + m], a1[r], sDv[4+r][m]);
            }
        }
    }
    #pragma unroll 2
    for (int k = 0; k < 8; ++k) {
        const int t16 = 112 + wave + (k << 2);
        f32x4 a0, a1; tile_mfma(t16, a0, a1);
        const int u = (t16 - 112) >> 1;
        #pragma unroll
        for (int r = 0; r < 4; ++r) {
            pA[r]   = fmaf(sXs1[rbase + r][u],      a0[r], pA[r]);
            pA[4+r] = fmaf(sXs1[16 + rbase + r][u], a1[r], pA[4+r]);
        }
    }

    const int wcol = c + ((wave & 1) << 4);
    #pragma unroll
    for (int rt = 0; rt < 2; ++rt) {
        #pragma unroll
        for (int r = 0; r < 4; ++r) {
            const int e = rt*16 + rbase + r;
            const int s = rt*4 + r;
            atomicAdd(&sMsg[e][wcol], pA[s]);
            const float s0 = sSh[e][0];
            atomicAdd(&sMsg[e][32 + c*3 + 0], sSh[e][1]*sC2[s] + s0*sDv[s][0]);
            atomicAdd(&sMsg[e][32 + c*3 + 1], sSh[e][2]*sC2[s] + s0*sDv[s][1]);
            atomicAdd(&sMsg[e][32 + c*3 + 2], sSh[e][3]*sC2[s] + s0*sDv[s][2]);
        }
    }
    __syncthreads();

    if (MODE == 0) {
        for (int i = tid; i < TE*DIMV; i += 256) {
            int e = i / DIMV, k = i - e*DIMV;
            atomicAdd(&sums[sDst[e]*DIMV + k], NORMF * sMsg[e][k]);
        }
        if (tid < TE) atomicAdd(&cnt[sDst[tid]], 1.0f);
    } else {
        // segment-reduce runs of equal (sorted) dst -> one atomic per (dst,k)
        for (int i = tid; i < TE*DIMV; i += 256) {
            int e = i / DIMV, k = i - e*DIMV;
            int d = sDst[e];
            if (e > 0 && sDst[e-1] == d) continue;     // not a run leader
            float acc = sMsg[e][k];
            for (int j = e + 1; j < TE && sDst[j] == d; ++j) acc += sMsg[j][k];
            atomicAdd(&sums[d*DIMV + k], NORMF * acc);
        }
    }
}

// Node kernel: out = residual + sums/max(cnt,1)
__global__ __launch_bounds__(256) void node_kernel(
    const float* __restrict__ x_dst, const float* __restrict__ rw0,
    const float* __restrict__ rw1, const float* __restrict__ sums,
    const float* __restrict__ cnt, float* __restrict__ out)
{
    int gid = blockIdx.x*256 + threadIdx.x;
    if (gid >= N_NODES*DIMV) return;
    int n = gid / DIMV;
    int k = gid - n*DIMV;
    const float* xd = x_dst + n*DIMV;
    float r = 0.f;
    if (k < 32) {
        #pragma unroll
        for (int u = 0; u < 32; ++u) r = fmaf(xd[u], rw0[u*32 + k], r);
        r *= RS32;
    } else {
        int kk = k - 32;
        int w = kk / 3, m = kk - w*3;
        #pragma unroll
        for (int u = 0; u < 16; ++u) r = fmaf(xd[32 + u*3 + m], rw1[u*16 + w], r);
        r *= RS16;
    }
    float cc = cnt[n];
    out[gid] = r + sums[gid] / fmaxf(cc, 1.f);
}

extern "C" void kernel_launch(void* const* d_in, const int* in_sizes, int n_in,
                              void* d_out, int out_size, void* d_ws, size_t ws_size,
                              hipStream_t stream) {
    const int*   dst   = (const int*)  d_in[0];
    const float* x_src = (const float*)d_in[1];
    const float* x_dst = (const float*)d_in[2];
    const float* sh    = (const float*)d_in[3];
    const float* ea    = (const float*)d_in[4];
    const float* W1    = (const float*)d_in[5];
    const float* b1    = (const float*)d_in[6];
    const float* W2    = (const float*)d_in[7];
    const float* b2    = (const float*)d_in[8];
    const float* rw0   = (const float*)d_in[9];
    const float* rw1   = (const float*)d_in[10];
    float* out = (float*)d_out;
    char*  ws  = (char*)d_ws;

    size_t off = 0;
    auto alloc = [&](size_t bytes) { size_t o = off; off = (off + bytes + 255) & ~255ULL; return o; };
    size_t o_w2t  = alloc((size_t)WNUM*HID*2);        // 0.29 MB
    size_t o_sums = alloc((size_t)N_NODES*DIMV*4);    // 3.2 MB
    size_t o_hist = alloc((size_t)N_NODES*4);
    size_t o_offs = alloc((size_t)N_NODES*4);
    size_t o_cur  = alloc((size_t)N_NODES*4);
    size_t o_cntf = alloc((size_t)N_NODES*4);
    size_t o_eidx = alloc((size_t)E_TOT*4);           // 0.4 MB
    const bool use_sorted = (off <= ws_size);         // ~4.1 MB total

    ushort* W2T   = (ushort*)(ws + o_w2t);
    float*  sums  = (float*) (ws + o_sums);

    if (use_sorted) {
        int*   histp = (int*)  (ws + o_hist);
        int*   offsp = (int*)  (ws + o_offs);
        int*   curp  = (int*)  (ws + o_cur);
        float* cntf  = (float*)(ws + o_cntf);
        int*   eidx  = (int*)  (ws + o_eidx);

        hipMemsetAsync(sums,  0, (size_t)N_NODES*DIMV*4, stream);
        hipMemsetAsync(histp, 0, (size_t)N_NODES*4, stream);
        hipMemsetAsync(curp,  0, (size_t)N_NODES*4, stream);
        prep_w2t<<<WNUM/64, 256, 0, stream>>>(W2, W2T);
        hist_kernel<<<(E_TOT + 255)/256, 256, 0, stream>>>(dst, histp);
        scan_kernel<<<1, 256, 0, stream>>>(histp, offsp, cntf);
        scatter_kernel<<<(E_TOT + 255)/256, 256, 0, stream>>>(dst, curp, offsp, eidx);
        edge_kernel<1><<<E_TOT/TE, 256, 0, stream>>>(dst, eidx, x_src, sh, ea,
                                                     W1, b1, W2T, b2, sums, nullptr);
        node_kernel<<<(N_NODES*DIMV + 255)/256, 256, 0, stream>>>(x_dst, rw0, rw1, sums, cntf, out);
    } else {
        // round-5 fallback: per-lane atomic scatter, minimal footprint
        float* cnt = (float*)(ws + o_hist);           // reuse
        hipMemsetAsync(sums, 0, (size_t)N_NODES*DIMV*4, stream);
        hipMemsetAsync(cnt,  0, (size_t)N_NODES*4, stream);
        prep_w2t<<<WNUM/64, 256, 0, stream>>>(W2, W2T);
        edge_kernel<0><<<E_TOT/TE, 256, 0, stream>>>(dst, nullptr, x_src, sh, ea,
                                                     W1, b1, W2T, b2, sums, cnt);
        node_kernel<<<(N_NODES*DIMV + 255)/256, 256, 0, stream>>>(x_dst, rw0, rw1, sums, cnt, out);
    }
}

// Round 8
// 383.430 us; speedup vs baseline: 1.2869x; 1.2869x over previous
//
#include <hip/hip_runtime.h>
#include <hip/hip_bf16.h>

#define E_TOT   100000
#define N_NODES 10000
#define DIMV    80
#define HID     64
#define EDIM    32
#define WNUM    2304
#define TE      32

static constexpr float NORMF      = 0.14433756729740643f;  // 1/sqrt(48)
static constexpr float INV_SQRT3F = 0.57735026918962576f;
static constexpr float RS32       = 0.17677669529663687f;  // 1/sqrt(32)
static constexpr float RS16       = 0.25f;                 // 1/sqrt(16)

typedef __attribute__((ext_vector_type(8))) short bf16x8;
typedef __attribute__((ext_vector_type(4))) float f32x4;

static __device__ __forceinline__ ushort f2bf(float v) {
    __hip_bfloat16 h(v);
    return *reinterpret_cast<ushort*>(&h);
}

// Coalesced transpose + bf16 convert: W2 (HID x WNUM fp32) -> W2T (WNUM x HID bf16)
__global__ __launch_bounds__(256) void prep_w2t(const float* __restrict__ W2,
                                                ushort* __restrict__ W2T) {
    __shared__ float sT[64][65];
    const int j0 = blockIdx.x * 64;
    #pragma unroll
    for (int k = 0; k < 16; ++k) {
        int idx = threadIdx.x + k*256;
        int t = idx >> 6, j = idx & 63;
        sT[j][t] = W2[t*WNUM + j0 + j];
    }
    __syncthreads();
    #pragma unroll
    for (int k = 0; k < 16; ++k) {
        int idx = threadIdx.x + k*256;
        int j = idx >> 6, t = idx & 63;
        W2T[(size_t)(j0 + j)*64 + t] = f2bf(sT[j][t]);
    }
}

// Edge kernel: block = 32 edges, 4 waves. Single fully-unrolled 36-tile loop
// (region dispatch constant-folds on k), 1-tile-ahead register prefetch of
// (bf0,bf1,bv). NO launch_bounds reg cap -> no spill. Atomic scatter at end.
__global__ __launch_bounds__(256) void edge_kernel(
    const int* __restrict__ dst, const float* __restrict__ x_src,
    const float* __restrict__ sh, const float* __restrict__ ea,
    const float* __restrict__ W1, const float* __restrict__ b1,
    const ushort* __restrict__ W2T, const float* __restrict__ b2,
    float* __restrict__ sums, float* __restrict__ cnt)
{
    __shared__ float  sX[TE][81];
    __shared__ float  sSh[TE][4];
    __shared__ float  sXs1[TE][17];
    __shared__ float  sEcA[TE][33];
    __shared__ ushort sHbf[TE][HID];
    __shared__ float  sMsg[TE][84];
    __shared__ int    sDst[TE];

    const int tid  = threadIdx.x;
    const int lane = tid & 63;
    const int wave = tid >> 6;
    const int e0   = blockIdx.x * TE;

    for (int i = tid; i < TE*DIMV; i += 256) { int e = i/80, k = i-e*80; sX[e][k] = x_src[e0*DIMV + i]; }
    for (int i = tid; i < TE*EDIM; i += 256) { int e = i>>5, k = i&31; sEcA[e][k] = ea[e0*EDIM + i]; }
    for (int i = tid; i < TE*4;    i += 256) sSh[0][i] = sh[e0*4 + i];
    if (tid < TE) sDst[tid] = dst[e0 + tid];
    __syncthreads();

    // layer 1: H = relu(ea @ W1 + b1)
    #pragma unroll
    for (int k = 0; k < (TE*HID)/256; ++k) {
        int idx = tid + k*256;
        int e = idx >> 6, t = idx & 63;
        float h = b1[t];
        #pragma unroll
        for (int i = 0; i < EDIM; ++i) h = fmaf(sEcA[e][i], W1[i*HID + t], h);
        sHbf[e][t] = f2bf(fmaxf(h, 0.f));
    }
    __syncthreads();

    for (int i = tid; i < TE*32; i += 256) {
        int e = i >> 5, u = i & 31;
        sEcA[e][u] = sSh[e][0] * sX[e][u];           // cA
    }
    for (int i = tid; i < TE*16; i += 256) {
        int e = i >> 4, u = i & 15;
        sXs1[e][u] = INV_SQRT3F * (sX[e][32+u*3+0]*sSh[e][1] +
                                   sX[e][32+u*3+1]*sSh[e][2] +
                                   sX[e][32+u*3+2]*sSh[e][3]);
    }
    for (int i = tid; i < TE*84; i += 256) sMsg[0][i] = 0.f;
    __syncthreads();

    // A fragments
    const int c     = lane & 15;
    const int g     = lane >> 4;
    const int rbase = g << 2;
    bf16x8 afrag[2][2];
    #pragma unroll
    for (int rt = 0; rt < 2; ++rt)
        #pragma unroll
        for (int kt = 0; kt < 2; ++kt)
            afrag[rt][kt] = *reinterpret_cast<const bf16x8*>(&sHbf[rt*16 + c][kt*32 + g*8]);

    float pA[8]     = {};
    float sC2[8]    = {};
    float sDv[8][3] = {};

    // ---- flattened 36-tile pipeline; tiles for this wave: t16 = wave + 4k.
    // Region by k (compile-time under full unroll): k<16 wa, k<24 wc, k<28 wd, else wb.
    bf16x8 nb0, nb1;
    float  nbv;
    {
        const int t16 = wave;
        const ushort* bp = W2T + (((size_t)((t16 << 4) + c)) << 6) + (g << 3);
        nb0 = *reinterpret_cast<const bf16x8*>(bp);
        nb1 = *reinterpret_cast<const bf16x8*>(bp + 32);
        nbv = b2[(t16 << 4) + c];
    }
    #pragma unroll
    for (int k = 0; k < 36; ++k) {
        const bf16x8 cb0 = nb0;
        const bf16x8 cb1 = nb1;
        const float  cbv = nbv;
        if (k < 35) {  // prefetch next tile
            const int t16n = wave + ((k + 1) << 2);
            const ushort* bp = W2T + (((size_t)((t16n << 4) + c)) << 6) + (g << 3);
            nb0 = *reinterpret_cast<const bf16x8*>(bp);
            nb1 = *reinterpret_cast<const bf16x8*>(bp + 32);
            nbv = b2[(t16n << 4) + c];
        }
        f32x4 a0 = {cbv, cbv, cbv, cbv};
        f32x4 a1 = {cbv, cbv, cbv, cbv};
        a0 = __builtin_amdgcn_mfma_f32_16x16x32_bf16(afrag[0][0], cb0, a0, 0, 0, 0);
        a0 = __builtin_amdgcn_mfma_f32_16x16x32_bf16(afrag[0][1], cb1, a0, 0, 0, 0);
        a1 = __builtin_amdgcn_mfma_f32_16x16x32_bf16(afrag[1][0], cb0, a1, 0, 0, 0);
        a1 = __builtin_amdgcn_mfma_f32_16x16x32_bf16(afrag[1][1], cb1, a1, 0, 0, 0);

        const int t16 = wave + (k << 2);
        if (k < 16) {            // wa: u = t16>>1
            const int u = t16 >> 1;
            #pragma unroll
            for (int r = 0; r < 4; ++r) {
                pA[r]   = fmaf(sEcA[rbase + r][u],      a0[r], pA[r]);
                pA[4+r] = fmaf(sEcA[16 + rbase + r][u], a1[r], pA[4+r]);
            }
        } else if (k < 24) {     // wc: u = t16-64
            const int u = t16 - 64;
            #pragma unroll
            for (int r = 0; r < 4; ++r) {
                sC2[r]   = fmaf(sX[rbase + r][u],      a0[r], sC2[r]);
                sC2[4+r] = fmaf(sX[16 + rbase + r][u], a1[r], sC2[4+r]);
            }
        } else if (k < 28) {     // wd: u = t16-96
            const int u = t16 - 96;
            #pragma unroll
            for (int r = 0; r < 4; ++r) {
                #pragma unroll
                for (int m = 0; m < 3; ++m) {
                    sDv[r][m]   = fmaf(sX[rbase + r][32 + u*3 + m],      a0[r], sDv[r][m]);
                    sDv[4+r][m] = fmaf(sX[16 + rbase + r][32 + u*3 + m], a1[r], sDv[4+r][m]);
                }
            }
        } else {                 // wb: u = (t16-112)>>1
            const int u = (t16 - 112) >> 1;
            #pragma unroll
            for (int r = 0; r < 4; ++r) {
                pA[r]   = fmaf(sXs1[rbase + r][u],      a0[r], pA[r]);
                pA[4+r] = fmaf(sXs1[16 + rbase + r][u], a1[r], pA[4+r]);
            }
        }
    }

    // ---- reduce partials into per-edge msg (LDS atomics)
    const int wcol = c + ((wave & 1) << 4);
    #pragma unroll
    for (int rt = 0; rt < 2; ++rt) {
        #pragma unroll
        for (int r = 0; r < 4; ++r) {
            const int e = rt*16 + rbase + r;
            const int s = rt*4 + r;
            atomicAdd(&sMsg[e][wcol], pA[s]);
            const float s0 = sSh[e][0];
            atomicAdd(&sMsg[e][32 + c*3 + 0], sSh[e][1]*sC2[s] + s0*sDv[s][0]);
            atomicAdd(&sMsg[e][32 + c*3 + 1], sSh[e][2]*sC2[s] + s0*sDv[s][1]);
            atomicAdd(&sMsg[e][32 + c*3 + 2], sSh[e][3]*sC2[s] + s0*sDv[s][2]);
        }
    }
    __syncthreads();

    // ---- scatter to node sums (fold NORM)
    for (int i = tid; i < TE*DIMV; i += 256) {
        int e = i / DIMV, k = i - e*DIMV;
        atomicAdd(&sums[sDst[e]*DIMV + k], NORMF * sMsg[e][k]);
    }
    if (tid < TE) atomicAdd(&cnt[sDst[tid]], 1.0f);
}

// Node kernel: out = residual + sums/max(cnt,1)
__global__ __launch_bounds__(256) void node_kernel(
    const float* __restrict__ x_dst, const float* __restrict__ rw0,
    const float* __restrict__ rw1, const float* __restrict__ sums,
    const float* __restrict__ cnt, float* __restrict__ out)
{
    int gid = blockIdx.x*256 + threadIdx.x;
    if (gid >= N_NODES*DIMV) return;
    int n = gid / DIMV;
    int k = gid - n*DIMV;
    const float* xd = x_dst + n*DIMV;
    float r = 0.f;
    if (k < 32) {
        #pragma unroll
        for (int u = 0; u < 32; ++u) r = fmaf(xd[u], rw0[u*32 + k], r);
        r *= RS32;
    } else {
        int kk = k - 32;
        int w = kk / 3, m = kk - w*3;
        #pragma unroll
        for (int u = 0; u < 16; ++u) r = fmaf(xd[32 + u*3 + m], rw1[u*16 + w], r);
        r *= RS16;
    }
    float cc = cnt[n];
    out[gid] = r + sums[gid] / fmaxf(cc, 1.f);
}

extern "C" void kernel_launch(void* const* d_in, const int* in_sizes, int n_in,
                              void* d_out, int out_size, void* d_ws, size_t ws_size,
                              hipStream_t stream) {
    const int*   dst   = (const int*)  d_in[0];
    const float* x_src = (const float*)d_in[1];
    const float* x_dst = (const float*)d_in[2];
    const float* sh    = (const float*)d_in[3];
    const float* ea    = (const float*)d_in[4];
    const float* W1    = (const float*)d_in[5];
    const float* b1    = (const float*)d_in[6];
    const float* W2    = (const float*)d_in[7];
    const float* b2    = (const float*)d_in[8];
    const float* rw0   = (const float*)d_in[9];
    const float* rw1   = (const float*)d_in[10];
    float* out  = (float*)d_out;
    char*  ws   = (char*)d_ws;

    float*  sums = (float*)ws;                                    // 3.2 MB
    float*  cnt  = sums + (size_t)N_NODES*DIMV;                   // 40 KB
    ushort* W2T  = (ushort*)(ws + (size_t)(N_NODES*DIMV + N_NODES)*sizeof(float));

    hipMemsetAsync(ws, 0, (size_t)(N_NODES*DIMV + N_NODES)*sizeof(float), stream);
    prep_w2t<<<WNUM/64, 256, 0, stream>>>(W2, W2T);
    edge_kernel<<<E_TOT/TE, 256, 0, stream>>>(dst, x_src, sh, ea, W1, b1, W2T, b2, sums, cnt);
    node_kernel<<<(N_NODES*DIMV + 255)/256, 256, 0, stream>>>(x_dst, rw0, rw1, sums, cnt, out);
}